// Round 8
// baseline (340.998 us; speedup 1.0000x reference)
//
#include <hip/hip_runtime.h>
#include <hip/hip_bf16.h>
#include <stdint.h>

#define B_ 4
#define H_ 16
#define L_ 2048
#define D_ 64
#define BH (B_ * H_)
#define NT (BH * 32)   // 64x64 tiles per tensor = 2048

typedef __attribute__((ext_vector_type(8))) short short8;
typedef __attribute__((ext_vector_type(4))) float f32x4;

__device__ __forceinline__ short b16(float f) {
  __hip_bfloat16 h = __float2bfloat16(f);
  return __builtin_bit_cast(short, h);
}
__device__ __forceinline__ unsigned int pkbf16(float lo, float hi) {
  return (unsigned int)(unsigned short)b16(lo) |
         ((unsigned int)(unsigned short)b16(hi) << 16);
}

// ---- merged prepass ----
// blocks [0,NT):   K fp32 [bh][k][d] -> Kt bf16 same layout (elementwise)
// blocks [NT,2NT): V fp32 [bh][k][d] -> Vt bf16 [bh][d][k] (transpose)
__global__ __launch_bounds__(256) void prep_kernel(const float* __restrict__ K,
                                                   const float* __restrict__ V,
                                                   unsigned short* __restrict__ Kt,
                                                   unsigned short* __restrict__ Vt) {
  __shared__ unsigned short lds[64 * 68];
  int bid = blockIdx.x;
  int t   = threadIdx.x;
  if (bid < NT) {
    const float* src = K + (size_t)bid * 64 * D_;
    unsigned short* dst = Kt + (size_t)bid * 64 * D_;
#pragma unroll
    for (int i = 0; i < 4; ++i) {
      int f4 = i * 256 + t;
      float4 v = *reinterpret_cast<const float4*>(src + f4 * 4);
      ushort4 u;
      u.x = (unsigned short)b16(v.x);
      u.y = (unsigned short)b16(v.y);
      u.z = (unsigned short)b16(v.z);
      u.w = (unsigned short)b16(v.w);
      *reinterpret_cast<ushort4*>(dst + f4 * 4) = u;
    }
  } else {
    bid -= NT;
    int bh = bid >> 5;
    int kt = bid & 31;
    const float* vsrc = V + ((size_t)bh * L_ + (size_t)kt * 64) * D_;
#pragma unroll
    for (int i = 0; i < 4; ++i) {
      int f4  = i * 256 + t;
      int row = f4 >> 4;
      int c4  = (f4 & 15) << 2;
      float4 v = *reinterpret_cast<const float4*>(vsrc + row * D_ + c4);
      ushort4 u;
      u.x = (unsigned short)b16(v.x);
      u.y = (unsigned short)b16(v.y);
      u.z = (unsigned short)b16(v.z);
      u.w = (unsigned short)b16(v.w);
      *reinterpret_cast<ushort4*>(&lds[row * 68 + c4]) = u;
    }
    __syncthreads();
    unsigned short* dst = Vt + (size_t)bh * D_ * L_ + (size_t)kt * 64;
#pragma unroll
    for (int i = 0; i < 8; ++i) {
      int c  = i * 256 + t;
      int d  = c >> 5;
      int k2 = (c & 31) * 2;
      unsigned int lo = lds[(k2 + 0) * 68 + d];
      unsigned int hi = lds[(k2 + 1) * 68 + d];
      *reinterpret_cast<unsigned int*>(dst + d * L_ + k2) = lo | (hi << 16);
    }
  }
}

// ---- fused sigmoid-attention: 2-head blocks (mask L1-shared), bf16 K/V staging,
// wave = 16-q strip x 64 k, in-wave P repack, 1 barrier/iter ----
__global__ __launch_bounds__(512, 4) void attn7_kernel(
    const float* __restrict__ Q, const int* __restrict__ M,
    const unsigned short* __restrict__ Kt, const unsigned short* __restrict__ Vt,
    float* __restrict__ O, float* __restrict__ A) {
  __shared__ unsigned short Kl[2][2][4096];  // [head][buf]
  __shared__ unsigned short Vl[2][2][4096];

  // XCD decode: grid 1024 = 8 xcd * 128. Per XCD: one b, 16 qt, 8 head-pairs.
  int wg  = blockIdx.x;
  int xcd = wg & 7;
  int j   = wg >> 3;            // 0..127
  int g   = xcd * 16 + (j & 15);  // 0..127
  int b   = g >> 5;
  int qt  = g & 31;
  int hp  = j >> 4;             // 0..7
  int bh0 = b * 16 + hp * 2;

  int t    = threadIdx.x;
  int lane = t & 63;
  int w    = t >> 6;     // 0..7
  int head = w >> 2;     // compute head for this wave
  int strip = w & 3;
  int lr   = lane & 15;
  int lg   = lane >> 4;
  int qrow0 = qt * 64 + strip * 16;
  int bh   = bh0 + head;

  // Q fragments (B-operand): q = qrow0+lr, d = ks*32+lg*8, temperature folded
  short8 qf[2];
  {
    const float* qb = Q + ((size_t)bh * L_ + qrow0 + lr) * D_;
#pragma unroll
    for (int ks = 0; ks < 2; ++ks) {
      const float4* p = reinterpret_cast<const float4*>(qb + ks * 32 + lg * 8);
      float4 a = p[0], c = p[1];
      qf[ks] = (short8){b16(a.x * 0.125f), b16(a.y * 0.125f), b16(a.z * 0.125f), b16(a.w * 0.125f),
                        b16(c.x * 0.125f), b16(c.y * 0.125f), b16(c.z * 0.125f), b16(c.w * 0.125f)};
    }
  }

  f32x4 o[4] = {};
  const int* mbase = M + (size_t)b * L_ * L_;
  float* abase = A + (size_t)bh * L_ * L_;

  // staging role: th in [0,256) stages head hd's tiles
  int th = t & 255, hd = t >> 8;
  int srow[2], sc0[2];
#pragma unroll
  for (int i = 0; i < 2; ++i) {
    int g2  = i * 256 + th;
    srow[i] = g2 >> 3;
    sc0[i]  = (g2 & 7) << 3;
  }
  const unsigned short* ktb = Kt + (size_t)(bh0 + hd) * L_ * D_;  // [k][d] bf16
  const unsigned short* vtb = Vt + (size_t)(bh0 + hd) * D_ * L_;  // [d][k] bf16

  // bpermute source-lane byte indices
  int srcA = (lr + 16 * (2 * (lg & 1))) << 2;
  int srcB = srcA + 64;
  bool hin = (lg & 2) != 0;

  uint4 kpre[2], vpre[2];

  // prologue: tile 0 -> LDS buf 0
#pragma unroll
  for (int i = 0; i < 2; ++i) {
    kpre[i] = *reinterpret_cast<const uint4*>(ktb + (size_t)srow[i] * D_ + sc0[i]);
    vpre[i] = *reinterpret_cast<const uint4*>(vtb + (size_t)srow[i] * L_ + sc0[i]);
  }
#pragma unroll
  for (int i = 0; i < 2; ++i) {
    int sw = sc0[i] ^ ((srow[i] & 7) << 3);
    *reinterpret_cast<uint4*>(&Kl[hd][0][srow[i] * 64 + sw]) = kpre[i];
    *reinterpret_cast<uint4*>(&Vl[hd][0][srow[i] * 64 + sw]) = vpre[i];
  }
  __syncthreads();

  for (int ki = 0; ki < 32; ++ki) {
    int cur = ki & 1;
    int k0  = ki * 64;

    // (1) mask loads FIRST (identical addresses for the two head-waves -> L1 dedup)
    int4 mv[4];
#pragma unroll
    for (int n = 0; n < 4; ++n)
      mv[n] = *reinterpret_cast<const int4*>(
          mbase + (size_t)(qrow0 + lr) * L_ + k0 + n * 16 + lg * 4);

    // (2) next-tile staging loads (drain at ds_write after PV)
    if (ki + 1 < 32) {
#pragma unroll
      for (int i = 0; i < 2; ++i) {
        kpre[i] = *reinterpret_cast<const uint4*>(ktb + (size_t)(k0 + 64 + srow[i]) * D_ + sc0[i]);
        vpre[i] = *reinterpret_cast<const uint4*>(vtb + (size_t)srow[i] * L_ + k0 + 64 + sc0[i]);
      }
    }

    // (3) S^T = K Q^T : s[n] row k = n*16+lg*4+r, col q = lr
    f32x4 s[4] = {};
#pragma unroll
    for (int ks = 0; ks < 2; ++ks) {
#pragma unroll
      for (int n = 0; n < 4; ++n) {
        int row = n * 16 + lr;
        int col = ks * 32 + lg * 8;
        short8 kf = *reinterpret_cast<const short8*>(
            &Kl[head][cur][row * 64 + (col ^ ((row & 7) << 3))]);
        s[n] = __builtin_amdgcn_mfma_f32_16x16x32_bf16(kf, qf[ks], s[n], 0, 0, 0);
      }
    }

    // (4) mask + sigmoid; attn f32x4 nt-store; pack P to bf16 dwords
    unsigned int c[4][2];
#pragma unroll
    for (int n = 0; n < 4; ++n) {
      f32x4 f;
#pragma unroll
      for (int r = 0; r < 4; ++r) {
        float sv = s[n][r];
        float e  = __builtin_amdgcn_exp2f(sv * -1.44269504f);
        float at = ((&mv[n].x)[r] != 0) ? __builtin_amdgcn_rcpf(1.0f + e) : 0.0f;
        f[r] = at;
      }
      __builtin_nontemporal_store(f, reinterpret_cast<f32x4*>(
          abase + (size_t)(qrow0 + lr) * L_ + k0 + n * 16 + lg * 4));
      c[n][0] = pkbf16(f[0], f[1]);
      c[n][1] = pkbf16(f[2], f[3]);
    }

    // (5) intra-wave repack: pf[ks].w[i] = c[2ks+(lg>>1)][i&1] via ds_bpermute
    short8 pf[2];
#pragma unroll
    for (int ks = 0; ks < 2; ++ks) {
      unsigned int wv[4];
#pragma unroll
      for (int i = 0; i < 4; ++i) {
        int idx = (i >> 1) ? srcB : srcA;
        int lo = __builtin_amdgcn_ds_bpermute(idx, (int)c[2 * ks][i & 1]);
        int hi = __builtin_amdgcn_ds_bpermute(idx, (int)c[2 * ks + 1][i & 1]);
        wv[i] = (unsigned int)(hin ? hi : lo);
      }
      uint4 u4 = {wv[0], wv[1], wv[2], wv[3]};
      pf[ks] = __builtin_bit_cast(short8, u4);
    }

    // (6) O += P V
#pragma unroll
    for (int ks = 0; ks < 2; ++ks) {
#pragma unroll
      for (int n2 = 0; n2 < 4; ++n2) {
        int row = n2 * 16 + lr;
        int col = ks * 32 + lg * 8;
        short8 vf = *reinterpret_cast<const short8*>(
            &Vl[head][cur][row * 64 + (col ^ ((row & 7) << 3))]);
        o[n2] = __builtin_amdgcn_mfma_f32_16x16x32_bf16(pf[ks], vf, o[n2], 0, 0, 0);
      }
    }

    // (7) write next tile -> other LDS buffer
    if (ki + 1 < 32) {
#pragma unroll
      for (int i = 0; i < 2; ++i) {
        int sw = sc0[i] ^ ((srow[i] & 7) << 3);
        *reinterpret_cast<uint4*>(&Kl[hd][cur ^ 1][srow[i] * 64 + sw]) = kpre[i];
        *reinterpret_cast<uint4*>(&Vl[hd][cur ^ 1][srow[i] * 64 + sw]) = vpre[i];
      }
    }
    __syncthreads();
  }

  // ---- epilogue: write O ----
  float* obase = O + ((size_t)bh * L_ + qrow0) * D_;
#pragma unroll
  for (int n2 = 0; n2 < 4; ++n2)
#pragma unroll
    for (int r = 0; r < 4; ++r)
      __builtin_nontemporal_store(o[n2][r],
          &obase[(lg * 4 + r) * D_ + n2 * 16 + lr]);
}

extern "C" void kernel_launch(void* const* d_in, const int* in_sizes, int n_in,
                              void* d_out, int out_size, void* d_ws, size_t ws_size,
                              hipStream_t stream) {
  (void)in_sizes; (void)n_in; (void)out_size; (void)ws_size;
  const float* Q = (const float*)d_in[0];
  const float* K = (const float*)d_in[1];
  const float* V = (const float*)d_in[2];
  const int*   M = (const int*)d_in[3];
  float* O = (float*)d_out;
  float* A = (float*)d_out + (size_t)BH * L_ * D_;
  unsigned short* Kt = (unsigned short*)d_ws;                        // 16.8 MB
  unsigned short* Vt = (unsigned short*)d_ws + (size_t)NT * 4096;    // 16.8 MB

  prep_kernel<<<2 * NT, 256, 0, stream>>>(K, V, Kt, Vt);
  attn7_kernel<<<NT / 2, 512, 0, stream>>>(Q, M, Kt, Vt, O, A);
}